// Round 2
// baseline (692.411 us; speedup 1.0000x reference)
//
#include <hip/hip_runtime.h>
#include <cstddef>

#define HW    4096
#define NPIX  16384
#define CCH   256

__device__ __forceinline__ float gelu_f(float x){
    // exact gelu (approximate=False): 0.5*x*(1+erf(x/sqrt(2)))
    return 0.5f * x * (1.0f + erff(x * 0.70710678118654752f));
}

// ---------------- transpose NCHW -> NHWC ----------------
__global__ __launch_bounds__(256) void k_transpose(const float* __restrict__ in,
                                                   float* __restrict__ out){
    __shared__ float tile[64][65];
    const int b = blockIdx.z, c0 = blockIdx.y * 64, hw0 = blockIdx.x * 64;
    const int tx = threadIdx.x & 63, tg = threadIdx.x >> 6;
    #pragma unroll
    for (int i = 0; i < 16; i++){
        const int c_l = tg * 16 + i;
        tile[c_l][tx] = in[(size_t)(b * CCH + c0 + c_l) * HW + hw0 + tx];
    }
    __syncthreads();
    #pragma unroll
    for (int i = 0; i < 16; i++){
        const int hw_l = tg * 16 + i;
        out[(size_t)(b * HW + hw0 + hw_l) * CCH + c0 + tx] = tile[tx][hw_l];
    }
}

// ---------------- tiled fp32 GEMM: out(N x M) = A(N x 256) @ W(256 x M) + bias ----------------
// EPI: 0 = bias, 1 = bias+gelu, 2 = bias + residual + NCHW-layout write
// MUL: A is multiplied elementwise by A2 while staging (u * attn fusion)
// Tile 128x128, micro 8x8 (2x2 blocks of 4x4 for conflict-free LDS reads)
template<int EPI, bool MUL>
__global__ __launch_bounds__(256) void k_gemm(
    const float* __restrict__ A, const float* __restrict__ A2,
    const float* __restrict__ Wt, const float* __restrict__ bias,
    const float* __restrict__ resid, float* __restrict__ out,
    const int M, const int ldc)
{
    __shared__ float As[16][128];
    __shared__ float Ws[16][128];
    const int n0 = blockIdx.x * 128;
    const int m0 = blockIdx.y * 128;
    const int t  = threadIdx.x;
    const int tx = t & 15, ty = t >> 4;

    // A staging: thread loads 8 consecutive k of one row
    const int a_n = t >> 1;
    const int a_k = (t & 1) * 8;
    const float* Ap  = A + (size_t)(n0 + a_n) * 256 + a_k;
    const float* A2p = MUL ? (A2 + (size_t)(n0 + a_n) * 256 + a_k) : nullptr;
    // W staging: thread loads 8 consecutive m of one k-row
    const int w_k = t >> 4;
    const int w_m = (t & 15) * 8;

    float acc[8][8] = {};

    for (int kt = 0; kt < 256; kt += 16){
        float4 av0 = *reinterpret_cast<const float4*>(Ap + kt);
        float4 av1 = *reinterpret_cast<const float4*>(Ap + kt + 4);
        if (MUL){
            const float4 u0 = *reinterpret_cast<const float4*>(A2p + kt);
            const float4 u1 = *reinterpret_cast<const float4*>(A2p + kt + 4);
            av0.x *= u0.x; av0.y *= u0.y; av0.z *= u0.z; av0.w *= u0.w;
            av1.x *= u1.x; av1.y *= u1.y; av1.z *= u1.z; av1.w *= u1.w;
        }
        const int wcol = m0 + w_m;
        const float* wrow = Wt + (size_t)(kt + w_k) * M;
        float wv[8];
        if (wcol + 8 <= M){
            const float4 w0 = *reinterpret_cast<const float4*>(wrow + wcol);
            const float4 w1 = *reinterpret_cast<const float4*>(wrow + wcol + 4);
            wv[0]=w0.x; wv[1]=w0.y; wv[2]=w0.z; wv[3]=w0.w;
            wv[4]=w1.x; wv[5]=w1.y; wv[6]=w1.z; wv[7]=w1.w;
        } else {
            #pragma unroll
            for (int q = 0; q < 8; q++) wv[q] = (wcol + q < M) ? wrow[wcol + q] : 0.f;
        }
        __syncthreads();
        As[a_k+0][a_n]=av0.x; As[a_k+1][a_n]=av0.y; As[a_k+2][a_n]=av0.z; As[a_k+3][a_n]=av0.w;
        As[a_k+4][a_n]=av1.x; As[a_k+5][a_n]=av1.y; As[a_k+6][a_n]=av1.z; As[a_k+7][a_n]=av1.w;
        #pragma unroll
        for (int q = 0; q < 8; q++) Ws[w_k][w_m + q] = wv[q];
        __syncthreads();
        #pragma unroll
        for (int kk = 0; kk < 16; kk++){
            const float4 a0 = *reinterpret_cast<const float4*>(&As[kk][ty * 4]);
            const float4 a1 = *reinterpret_cast<const float4*>(&As[kk][64 + ty * 4]);
            const float4 b0 = *reinterpret_cast<const float4*>(&Ws[kk][tx * 4]);
            const float4 b1 = *reinterpret_cast<const float4*>(&Ws[kk][64 + tx * 4]);
            const float ar[8] = {a0.x,a0.y,a0.z,a0.w,a1.x,a1.y,a1.z,a1.w};
            const float br[8] = {b0.x,b0.y,b0.z,b0.w,b1.x,b1.y,b1.z,b1.w};
            #pragma unroll
            for (int i = 0; i < 8; i++)
                #pragma unroll
                for (int j = 0; j < 8; j++)
                    acc[i][j] = fmaf(ar[i], br[j], acc[i][j]);
        }
    }

    if (EPI == 2){
        // write NCHW with residual: out[b, m, hw] = acc + bias[m] + resid[b, m, hw]
        const int bImg = n0 >> 12;
        const int hwb  = n0 & (HW - 1);
        #pragma unroll
        for (int jj = 0; jj < 8; jj++){
            const int m = m0 + (jj >> 2) * 64 + tx * 4 + (jj & 3);
            const float bs = bias[m];
            #pragma unroll
            for (int ri = 0; ri < 2; ri++){
                const int rbase = hwb + ri * 64 + ty * 4;
                const size_t addr = ((size_t)bImg * CCH + m) * HW + rbase;
                const float4 rv = *reinterpret_cast<const float4*>(&resid[addr]);
                float4 o;
                o.x = acc[ri*4+0][jj] + bs + rv.x;
                o.y = acc[ri*4+1][jj] + bs + rv.y;
                o.z = acc[ri*4+2][jj] + bs + rv.z;
                o.w = acc[ri*4+3][jj] + bs + rv.w;
                *reinterpret_cast<float4*>(&out[addr]) = o;
            }
        }
    } else {
        #pragma unroll
        for (int ii = 0; ii < 8; ii++){
            const int n = n0 + (ii >> 2) * 64 + ty * 4 + (ii & 3);
            #pragma unroll
            for (int cj = 0; cj < 2; cj++){
                const int m = m0 + cj * 64 + tx * 4;
                if (m >= M) continue;
                if (m + 4 <= M){
                    float v0 = acc[ii][cj*4+0] + bias[m+0];
                    float v1 = acc[ii][cj*4+1] + bias[m+1];
                    float v2 = acc[ii][cj*4+2] + bias[m+2];
                    float v3 = acc[ii][cj*4+3] + bias[m+3];
                    if (EPI == 1){ v0=gelu_f(v0); v1=gelu_f(v1); v2=gelu_f(v2); v3=gelu_f(v3); }
                    float4 o; o.x=v0; o.y=v1; o.z=v2; o.w=v3;
                    *reinterpret_cast<float4*>(&out[(size_t)n * ldc + m]) = o;
                } else {
                    #pragma unroll
                    for (int j = 0; j < 4; j++) if (m + j < M){
                        float v = acc[ii][cj*4+j] + bias[m+j];
                        if (EPI == 1) v = gelu_f(v);
                        out[(size_t)n * ldc + m + j] = v;
                    }
                }
            }
        }
    }
}

// ---------------- depthwise 5x5, pad 2, NHWC ----------------
__global__ __launch_bounds__(256) void k_dwconv5(const float* __restrict__ in,
                                                 const float* __restrict__ w,
                                                 const float* __restrict__ bias,
                                                 float* __restrict__ out){
    const int c = threadIdx.x;
    const int x = blockIdx.x, y = blockIdx.y, b = blockIdx.z;
    float acc = bias[c];
    #pragma unroll
    for (int dy = -2; dy <= 2; dy++){
        const int yy = y + dy;
        if ((unsigned)yy >= 64u) continue;
        #pragma unroll
        for (int dx = -2; dx <= 2; dx++){
            const int xx = x + dx;
            if ((unsigned)xx >= 64u) continue;
            acc = fmaf(in[(size_t)((b*64+yy)*64+xx) * CCH + c],
                       w[c*25 + (dy+2)*5 + (dx+2)], acc);
        }
    }
    out[(size_t)((b*64+y)*64+x) * CCH + c] = acc;
}

// ---------------- depthwise 3x3 + LayerNorm(channel) + GELU, NHWC ----------------
__global__ __launch_bounds__(256) void k_dw3_ln_gelu(const float* __restrict__ in,
                                                     const float* __restrict__ w3,
                                                     const float* __restrict__ b3,
                                                     const float* __restrict__ g,
                                                     const float* __restrict__ bta,
                                                     float* __restrict__ out){
    const int c = threadIdx.x;
    const int n = blockIdx.x;
    const int x = n & 63, y = (n >> 6) & 63, b = n >> 12;
    float acc = b3[c];
    #pragma unroll
    for (int dy = -1; dy <= 1; dy++){
        const int yy = y + dy;
        if ((unsigned)yy >= 64u) continue;
        #pragma unroll
        for (int dx = -1; dx <= 1; dx++){
            const int xx = x + dx;
            if ((unsigned)xx >= 64u) continue;
            acc = fmaf(in[(size_t)((b*64+yy)*64+xx) * CCH + c],
                       w3[c*9 + (dy+1)*3 + (dx+1)], acc);
        }
    }
    float s = acc, s2 = acc * acc;
    #pragma unroll
    for (int o = 32; o > 0; o >>= 1){
        s  += __shfl_down(s, o);
        s2 += __shfl_down(s2, o);
    }
    __shared__ float r1[4], r2[4];
    if ((c & 63) == 0){ r1[c >> 6] = s; r2[c >> 6] = s2; }
    __syncthreads();
    const float S  = r1[0] + r1[1] + r1[2] + r1[3];
    const float S2 = r2[0] + r2[1] + r2[2] + r2[3];
    const float mu  = S  * (1.f/256.f);
    const float var = S2 * (1.f/256.f) - mu * mu;
    const float xn = (acc - mu) * rsqrtf(var + 1e-5f) * g[c] + bta[c];
    out[(size_t)n * CCH + c] = gelu_f(xn);
}

// ---------------- softmax over P=9 per (pixel, group), in place on cols 144..215 ----------------
__global__ __launch_bounds__(256) void k_softmax9(float* __restrict__ om){
    const int idx = blockIdx.x * 256 + threadIdx.x;
    if (idx >= NPIX * 8) return;
    const int n = idx >> 3, gI = idx & 7;
    float* p = om + (size_t)n * 216 + 144 + gI * 9;
    float mx = p[0];
    #pragma unroll
    for (int i = 1; i < 9; i++) mx = fmaxf(mx, p[i]);
    float e[9], s = 0.f;
    #pragma unroll
    for (int i = 0; i < 9; i++){ e[i] = expf(p[i] - mx); s += e[i]; }
    const float inv = 1.f / s;
    #pragma unroll
    for (int i = 0; i < 9; i++) p[i] = e[i] * inv;
}

// ---------------- DCNv3 core: bilinear sample + mask-weighted sum ----------------
// padded coords: ix = x + 1 + (p/3 - 1) + off_x ; tap value = xproj[yi-1, xi-1] iff 1<=xi,yi<=64
__global__ __launch_bounds__(256) void k_dcn(const float* __restrict__ xproj,
                                             const float* __restrict__ om,
                                             float* __restrict__ out){
    const int n = blockIdx.x;
    const int t = threadIdx.x;
    const int gI = t >> 5, c = t & 31;
    const int x = n & 63, y = (n >> 6) & 63, b = n >> 12;
    const float* off = om + (size_t)n * 216 + gI * 18;
    const float* msk = om + (size_t)n * 216 + 144 + gI * 9;
    const float* base = xproj + (size_t)b * HW * CCH + gI * 32 + c;
    float acc = 0.f;
    #pragma unroll
    for (int p = 0; p < 9; p++){
        const float ix = (float)(x + p / 3) + off[p*2];      // padded-x
        const float iy = (float)(y + p % 3) + off[p*2+1];    // padded-y
        const float x0f = floorf(ix), y0f = floorf(iy);
        const int   x0 = (int)x0f,   y0 = (int)y0f;
        const float wx1 = ix - x0f,  wy1 = iy - y0f;
        const float wx0 = 1.f - wx1, wy0 = 1.f - wy1;
        const float mp = msk[p];
        const int ux = x0 - 1, uy = y0 - 1;                  // unpadded tap coords
        const bool X0 = (unsigned)ux     < 64u, X1 = (unsigned)(ux+1) < 64u;
        const bool Y0 = (unsigned)uy     < 64u, Y1 = (unsigned)(uy+1) < 64u;
        float v00 = 0.f, v01 = 0.f, v10 = 0.f, v11 = 0.f;
        if (X0 && Y0) v00 = base[(size_t)(uy    *64 + ux  ) * CCH];
        if (X1 && Y0) v01 = base[(size_t)(uy    *64 + ux+1) * CCH];
        if (X0 && Y1) v10 = base[(size_t)((uy+1)*64 + ux  ) * CCH];
        if (X1 && Y1) v11 = base[(size_t)((uy+1)*64 + ux+1) * CCH];
        acc = fmaf(mp, wx0*wy0*v00 + wx1*wy0*v01 + wx0*wy1*v10 + wx1*wy1*v11, acc);
    }
    out[(size_t)n * CCH + t] = acc;
}

extern "C" void kernel_launch(void* const* d_in, const int* in_sizes, int n_in,
                              void* d_out, int out_size, void* d_ws, size_t ws_size,
                              hipStream_t stream){
    const float* x         = (const float*)d_in[0];
    const float* proj1_w   = (const float*)d_in[1];
    const float* proj1_b   = (const float*)d_in[2];
    const float* conv0_w   = (const float*)d_in[3];
    const float* conv0_b   = (const float*)d_in[4];
    const float* inproj_w  = (const float*)d_in[5];
    const float* inproj_b  = (const float*)d_in[6];
    const float* dw_w      = (const float*)d_in[7];
    const float* dw_b      = (const float*)d_in[8];
    const float* ln_g      = (const float*)d_in[9];
    const float* ln_b      = (const float*)d_in[10];
    const float* off_w     = (const float*)d_in[11];
    const float* off_b     = (const float*)d_in[12];
    const float* mask_w    = (const float*)d_in[13];
    const float* mask_b    = (const float*)d_in[14];
    const float* outproj_w = (const float*)d_in[15];
    const float* outproj_b = (const float*)d_in[16];
    const float* conv_w    = (const float*)d_in[17];
    const float* conv_b    = (const float*)d_in[18];
    const float* proj2_w   = (const float*)d_in[19];
    const float* proj2_b   = (const float*)d_in[20];
    float* outp = (float*)d_out;

    const size_t NC = (size_t)NPIX * CCH;
    float* b0 = (float*)d_ws;      // x_t -> xproj -> attn
    float* b1 = b0 + NC;           // u (gelu(proj1)) — persists to the end
    float* b2 = b1 + NC;           // h5 -> offset/mask -> attn2
    float* b3 = outp;              // d_out doubles as scratch: x1 -> dcnout -> final

    // 1. x (NCHW) -> NHWC
    k_transpose<<<dim3(64,4,4),256,0,stream>>>(x, b0);
    // 2. u = gelu(x @ proj1_w + b)
    k_gemm<1,false><<<dim3(128,2),256,0,stream>>>(b0, nullptr, proj1_w, proj1_b, nullptr, b1, 256, 256);
    // 3. h5 = dwconv5x5(u)
    k_dwconv5<<<dim3(64,64,4),256,0,stream>>>(b1, conv0_w, conv0_b, b2);
    // 4. xproj = h5 @ inproj_w + b
    k_gemm<0,false><<<dim3(128,2),256,0,stream>>>(b2, nullptr, inproj_w, inproj_b, nullptr, b0, 256, 256);
    // 5. x1 = gelu(LN(dwconv3x3(h5)))
    k_dw3_ln_gelu<<<NPIX,256,0,stream>>>(b2, dw_w, dw_b, ln_g, ln_b, b3);
    // 6. offset cols [0,144) and mask logits cols [144,216) into b2 (ld 216)
    k_gemm<0,false><<<dim3(128,2),256,0,stream>>>(b3, nullptr, off_w,  off_b,  nullptr, b2,       144, 216);
    k_gemm<0,false><<<dim3(128,1),256,0,stream>>>(b3, nullptr, mask_w, mask_b, nullptr, b2 + 144,  72, 216);
    // 7. softmax over 9 per (pixel, group)
    k_softmax9<<<512,256,0,stream>>>(b2);
    // 8. DCN core
    k_dcn<<<NPIX,256,0,stream>>>(b0, b2, b3);
    // 9. attn = dcnout @ outproj_w + b
    k_gemm<0,false><<<dim3(128,2),256,0,stream>>>(b3, nullptr, outproj_w, outproj_b, nullptr, b0, 256, 256);
    // 10. attn2 = attn @ conv_w + b
    k_gemm<0,false><<<dim3(128,2),256,0,stream>>>(b0, nullptr, conv_w, conv_b, nullptr, b2, 256, 256);
    // 11. out = (u * attn2) @ proj2_w + b + x   (NCHW write, fused residual)
    k_gemm<2,true><<<dim3(128,2),256,0,stream>>>(b1, b2, proj2_w, proj2_b, x, outp, 256, 256);
}

// Round 3
// 486.669 us; speedup vs baseline: 1.4228x; 1.4228x over previous
//
#include <hip/hip_runtime.h>
#include <cstddef>

#define HW    4096
#define NPIX  16384
#define CCH   256

__device__ __forceinline__ float gelu_f(float x){
    // exact gelu (approximate=False): 0.5*x*(1+erf(x/sqrt(2)))
    return 0.5f * x * (1.0f + erff(x * 0.70710678118654752f));
}

// ---------------- weight transpose prep: w5 (256x25) -> wT (25x256); w3 (256x9) -> wT3 (9x256)
__global__ __launch_bounds__(256) void k_prep(const float* __restrict__ w5,
                                              const float* __restrict__ w3,
                                              float* __restrict__ wT,
                                              float* __restrict__ wT3){
    const int c = threadIdx.x;
    #pragma unroll
    for (int k = 0; k < 25; k++) wT[k * CCH + c] = w5[c * 25 + k];
    #pragma unroll
    for (int k = 0; k < 9;  k++) wT3[k * CCH + c] = w3[c * 9 + k];
}

// ---------------- transpose NCHW -> NHWC ----------------
__global__ __launch_bounds__(256) void k_transpose(const float* __restrict__ in,
                                                   float* __restrict__ out){
    __shared__ float tile[64][65];
    const int b = blockIdx.z, c0 = blockIdx.y * 64, hw0 = blockIdx.x * 64;
    const int tx = threadIdx.x & 63, tg = threadIdx.x >> 6;
    #pragma unroll
    for (int i = 0; i < 16; i++){
        const int c_l = tg * 16 + i;
        tile[c_l][tx] = in[(size_t)(b * CCH + c0 + c_l) * HW + hw0 + tx];
    }
    __syncthreads();
    #pragma unroll
    for (int i = 0; i < 16; i++){
        const int hw_l = tg * 16 + i;
        out[(size_t)(b * HW + hw0 + hw_l) * CCH + c0 + tx] = tile[tx][hw_l];
    }
}

// ---------------- tiled fp32 GEMM: out(N x M) = A(N x 256) @ W(256 x M) + bias ----------------
// EPI: 0 = bias, 1 = bias+gelu, 2 = bias + residual + NCHW-layout write
// MUL: A is multiplied elementwise by A2 while staging (u * attn fusion)
template<int EPI, bool MUL>
__global__ __launch_bounds__(256) void k_gemm(
    const float* __restrict__ A, const float* __restrict__ A2,
    const float* __restrict__ Wt, const float* __restrict__ bias,
    const float* __restrict__ resid, float* __restrict__ out,
    const int M, const int ldc)
{
    __shared__ float As[16][128];
    __shared__ float Ws[16][128];
    const int n0 = blockIdx.x * 128;
    const int m0 = blockIdx.y * 128;
    const int t  = threadIdx.x;
    const int tx = t & 15, ty = t >> 4;

    const int a_n = t >> 1;
    const int a_k = (t & 1) * 8;
    const float* Ap  = A + (size_t)(n0 + a_n) * 256 + a_k;
    const float* A2p = MUL ? (A2 + (size_t)(n0 + a_n) * 256 + a_k) : nullptr;
    const int w_k = t >> 4;
    const int w_m = (t & 15) * 8;

    float acc[8][8] = {};

    for (int kt = 0; kt < 256; kt += 16){
        float4 av0 = *reinterpret_cast<const float4*>(Ap + kt);
        float4 av1 = *reinterpret_cast<const float4*>(Ap + kt + 4);
        if (MUL){
            const float4 u0 = *reinterpret_cast<const float4*>(A2p + kt);
            const float4 u1 = *reinterpret_cast<const float4*>(A2p + kt + 4);
            av0.x *= u0.x; av0.y *= u0.y; av0.z *= u0.z; av0.w *= u0.w;
            av1.x *= u1.x; av1.y *= u1.y; av1.z *= u1.z; av1.w *= u1.w;
        }
        const int wcol = m0 + w_m;
        const float* wrow = Wt + (size_t)(kt + w_k) * M;
        float wv[8];
        if (wcol + 8 <= M){
            const float4 w0 = *reinterpret_cast<const float4*>(wrow + wcol);
            const float4 w1 = *reinterpret_cast<const float4*>(wrow + wcol + 4);
            wv[0]=w0.x; wv[1]=w0.y; wv[2]=w0.z; wv[3]=w0.w;
            wv[4]=w1.x; wv[5]=w1.y; wv[6]=w1.z; wv[7]=w1.w;
        } else {
            #pragma unroll
            for (int q = 0; q < 8; q++) wv[q] = (wcol + q < M) ? wrow[wcol + q] : 0.f;
        }
        __syncthreads();
        As[a_k+0][a_n]=av0.x; As[a_k+1][a_n]=av0.y; As[a_k+2][a_n]=av0.z; As[a_k+3][a_n]=av0.w;
        As[a_k+4][a_n]=av1.x; As[a_k+5][a_n]=av1.y; As[a_k+6][a_n]=av1.z; As[a_k+7][a_n]=av1.w;
        #pragma unroll
        for (int q = 0; q < 8; q++) Ws[w_k][w_m + q] = wv[q];
        __syncthreads();
        #pragma unroll
        for (int kk = 0; kk < 16; kk++){
            const float4 a0 = *reinterpret_cast<const float4*>(&As[kk][ty * 4]);
            const float4 a1 = *reinterpret_cast<const float4*>(&As[kk][64 + ty * 4]);
            const float4 b0 = *reinterpret_cast<const float4*>(&Ws[kk][tx * 4]);
            const float4 b1 = *reinterpret_cast<const float4*>(&Ws[kk][64 + tx * 4]);
            const float ar[8] = {a0.x,a0.y,a0.z,a0.w,a1.x,a1.y,a1.z,a1.w};
            const float br[8] = {b0.x,b0.y,b0.z,b0.w,b1.x,b1.y,b1.z,b1.w};
            #pragma unroll
            for (int i = 0; i < 8; i++)
                #pragma unroll
                for (int j = 0; j < 8; j++)
                    acc[i][j] = fmaf(ar[i], br[j], acc[i][j]);
        }
    }

    if (EPI == 2){
        const int bImg = n0 >> 12;
        const int hwb  = n0 & (HW - 1);
        #pragma unroll
        for (int jj = 0; jj < 8; jj++){
            const int m = m0 + (jj >> 2) * 64 + tx * 4 + (jj & 3);
            const float bs = bias[m];
            #pragma unroll
            for (int ri = 0; ri < 2; ri++){
                const int rbase = hwb + ri * 64 + ty * 4;
                const size_t addr = ((size_t)bImg * CCH + m) * HW + rbase;
                const float4 rv = *reinterpret_cast<const float4*>(&resid[addr]);
                float4 o;
                o.x = acc[ri*4+0][jj] + bs + rv.x;
                o.y = acc[ri*4+1][jj] + bs + rv.y;
                o.z = acc[ri*4+2][jj] + bs + rv.z;
                o.w = acc[ri*4+3][jj] + bs + rv.w;
                *reinterpret_cast<float4*>(&out[addr]) = o;
            }
        }
    } else {
        #pragma unroll
        for (int ii = 0; ii < 8; ii++){
            const int n = n0 + (ii >> 2) * 64 + ty * 4 + (ii & 3);
            #pragma unroll
            for (int cj = 0; cj < 2; cj++){
                const int m = m0 + cj * 64 + tx * 4;
                if (m >= M) continue;
                if (m + 4 <= M){
                    float v0 = acc[ii][cj*4+0] + bias[m+0];
                    float v1 = acc[ii][cj*4+1] + bias[m+1];
                    float v2 = acc[ii][cj*4+2] + bias[m+2];
                    float v3 = acc[ii][cj*4+3] + bias[m+3];
                    if (EPI == 1){ v0=gelu_f(v0); v1=gelu_f(v1); v2=gelu_f(v2); v3=gelu_f(v3); }
                    float4 o; o.x=v0; o.y=v1; o.z=v2; o.w=v3;
                    *reinterpret_cast<float4*>(&out[(size_t)n * ldc + m]) = o;
                } else {
                    #pragma unroll
                    for (int j = 0; j < 4; j++) if (m + j < M){
                        float v = acc[ii][cj*4+j] + bias[m+j];
                        if (EPI == 1) v = gelu_f(v);
                        out[(size_t)n * ldc + m + j] = v;
                    }
                }
            }
        }
    }
}

// ---------------- depthwise 5x5, pad 2, NHWC — branchless, float4 channels ----------------
// one wave = one pixel (lane = 4-channel group); weights from transposed wT[25][256]
__global__ __launch_bounds__(256) void k_dwconv5(const float* __restrict__ in,
                                                 const float* __restrict__ wT,
                                                 const float* __restrict__ bias,
                                                 float* __restrict__ out){
    const int lane = threadIdx.x & 63;
    const int pq   = threadIdx.x >> 6;
    const int n = blockIdx.x * 4 + pq;
    const int x = n & 63, y = (n >> 6) & 63, b = n >> 12;
    const int c = lane * 4;
    const float* bp = in + (size_t)(b * HW) * CCH + c;
    float4 acc = *reinterpret_cast<const float4*>(bias + c);
    #pragma unroll
    for (int k = 0; k < 25; k++){
        const int dy = k / 5 - 2, dx = k % 5 - 2;
        const int yy = y + dy, xx = x + dx;
        const float m = (((unsigned)yy < 64u) & ((unsigned)xx < 64u)) ? 1.f : 0.f;
        const int yc = min(max(yy, 0), 63), xc = min(max(xx, 0), 63);
        const float4 iv = *reinterpret_cast<const float4*>(bp + (size_t)(yc * 64 + xc) * CCH);
        const float4 wv = *reinterpret_cast<const float4*>(wT + k * CCH + c);
        acc.x = fmaf(iv.x, wv.x * m, acc.x);
        acc.y = fmaf(iv.y, wv.y * m, acc.y);
        acc.z = fmaf(iv.z, wv.z * m, acc.z);
        acc.w = fmaf(iv.w, wv.w * m, acc.w);
    }
    *reinterpret_cast<float4*>(out + (size_t)n * CCH + c) = acc;
}

// ---------------- depthwise 3x3 + LayerNorm(channel) + GELU — branchless, wave-reduce ----------------
__global__ __launch_bounds__(256) void k_dw3_ln_gelu(const float* __restrict__ in,
                                                     const float* __restrict__ wT3,
                                                     const float* __restrict__ b3,
                                                     const float* __restrict__ g,
                                                     const float* __restrict__ bta,
                                                     float* __restrict__ out){
    const int lane = threadIdx.x & 63;
    const int pq   = threadIdx.x >> 6;
    const int n = blockIdx.x * 4 + pq;
    const int x = n & 63, y = (n >> 6) & 63, b = n >> 12;
    const int c = lane * 4;
    const float* bp = in + (size_t)(b * HW) * CCH + c;
    float4 acc = *reinterpret_cast<const float4*>(b3 + c);
    #pragma unroll
    for (int k = 0; k < 9; k++){
        const int dy = k / 3 - 1, dx = k % 3 - 1;
        const int yy = y + dy, xx = x + dx;
        const float m = (((unsigned)yy < 64u) & ((unsigned)xx < 64u)) ? 1.f : 0.f;
        const int yc = min(max(yy, 0), 63), xc = min(max(xx, 0), 63);
        const float4 iv = *reinterpret_cast<const float4*>(bp + (size_t)(yc * 64 + xc) * CCH);
        const float4 wv = *reinterpret_cast<const float4*>(wT3 + k * CCH + c);
        acc.x = fmaf(iv.x, wv.x * m, acc.x);
        acc.y = fmaf(iv.y, wv.y * m, acc.y);
        acc.z = fmaf(iv.z, wv.z * m, acc.z);
        acc.w = fmaf(iv.w, wv.w * m, acc.w);
    }
    float s  = acc.x + acc.y + acc.z + acc.w;
    float s2 = acc.x*acc.x + acc.y*acc.y + acc.z*acc.z + acc.w*acc.w;
    #pragma unroll
    for (int o = 32; o > 0; o >>= 1){
        s  += __shfl_xor(s, o);
        s2 += __shfl_xor(s2, o);
    }
    const float mu  = s  * (1.f / 256.f);
    const float var = s2 * (1.f / 256.f) - mu * mu;
    const float r   = rsqrtf(var + 1e-5f);
    const float4 gv = *reinterpret_cast<const float4*>(g + c);
    const float4 bv = *reinterpret_cast<const float4*>(bta + c);
    float4 o;
    o.x = gelu_f((acc.x - mu) * r * gv.x + bv.x);
    o.y = gelu_f((acc.y - mu) * r * gv.y + bv.y);
    o.z = gelu_f((acc.z - mu) * r * gv.z + bv.z);
    o.w = gelu_f((acc.w - mu) * r * gv.w + bv.w);
    *reinterpret_cast<float4*>(out + (size_t)n * CCH + c) = o;
}

// ---------------- DCNv3 core: fused softmax + bilinear sample + mask-weighted sum ----------------
// branchless: clamped addresses, OOB folded into weights. lane = g*8 + cq (float4 chans)
__global__ __launch_bounds__(256) void k_dcn(const float* __restrict__ xproj,
                                             const float* __restrict__ om,
                                             float* __restrict__ out){
    const int lane = threadIdx.x & 63;
    const int pq   = threadIdx.x >> 6;
    const int n = blockIdx.x * 4 + pq;
    const int gI = lane >> 3, cq = lane & 7;
    const int x = n & 63, y = (n >> 6) & 63, b = n >> 12;
    const float* off = om + (size_t)n * 216 + gI * 18;
    const float* lg  = om + (size_t)n * 216 + 144 + gI * 9;
    // per-thread softmax over the 9 mask logits (redundant across 8 lanes, VALU-cheap)
    float l[9]; float mx = -1e30f;
    #pragma unroll
    for (int p = 0; p < 9; p++){ l[p] = lg[p]; mx = fmaxf(mx, l[p]); }
    float ssum = 0.f;
    #pragma unroll
    for (int p = 0; p < 9; p++){ l[p] = expf(l[p] - mx); ssum += l[p]; }
    const float inv = 1.f / ssum;
    const float* base = xproj + (size_t)b * HW * CCH + gI * 32 + cq * 4;
    float4 acc = {0.f, 0.f, 0.f, 0.f};
    #pragma unroll
    for (int p = 0; p < 9; p++){
        const float2 o2 = *reinterpret_cast<const float2*>(off + p * 2);
        const float ix = (float)(x + p / 3) + o2.x;   // padded-x
        const float iy = (float)(y + p % 3) + o2.y;   // padded-y
        const float x0f = floorf(ix), y0f = floorf(iy);
        const float wx1 = ix - x0f, wy1 = iy - y0f;
        const float wx0 = 1.f - wx1, wy0 = 1.f - wy1;
        const int ux = (int)x0f - 1, uy = (int)y0f - 1;   // unpadded
        const bool X0 = (unsigned)ux     < 64u, X1 = (unsigned)(ux+1) < 64u;
        const bool Y0 = (unsigned)uy     < 64u, Y1 = (unsigned)(uy+1) < 64u;
        const int ux0 = min(max(ux,     0), 63), ux1 = min(max(ux + 1, 0), 63);
        const int uy0 = min(max(uy,     0), 63), uy1 = min(max(uy + 1, 0), 63);
        const float mp = l[p] * inv;
        const float w00 = wx0 * wy0 * ((X0 & Y0) ? mp : 0.f);
        const float w01 = wx1 * wy0 * ((X1 & Y0) ? mp : 0.f);
        const float w10 = wx0 * wy1 * ((X0 & Y1) ? mp : 0.f);
        const float w11 = wx1 * wy1 * ((X1 & Y1) ? mp : 0.f);
        const float4 v00 = *reinterpret_cast<const float4*>(base + (size_t)(uy0 * 64 + ux0) * CCH);
        const float4 v01 = *reinterpret_cast<const float4*>(base + (size_t)(uy0 * 64 + ux1) * CCH);
        const float4 v10 = *reinterpret_cast<const float4*>(base + (size_t)(uy1 * 64 + ux0) * CCH);
        const float4 v11 = *reinterpret_cast<const float4*>(base + (size_t)(uy1 * 64 + ux1) * CCH);
        acc.x = fmaf(w00, v00.x, fmaf(w01, v01.x, fmaf(w10, v10.x, fmaf(w11, v11.x, acc.x))));
        acc.y = fmaf(w00, v00.y, fmaf(w01, v01.y, fmaf(w10, v10.y, fmaf(w11, v11.y, acc.y))));
        acc.z = fmaf(w00, v00.z, fmaf(w01, v01.z, fmaf(w10, v10.z, fmaf(w11, v11.z, acc.z))));
        acc.w = fmaf(w00, v00.w, fmaf(w01, v01.w, fmaf(w10, v10.w, fmaf(w11, v11.w, acc.w))));
    }
    *reinterpret_cast<float4*>(out + (size_t)n * CCH + gI * 32 + cq * 4) = acc;
}

extern "C" void kernel_launch(void* const* d_in, const int* in_sizes, int n_in,
                              void* d_out, int out_size, void* d_ws, size_t ws_size,
                              hipStream_t stream){
    const float* x         = (const float*)d_in[0];
    const float* proj1_w   = (const float*)d_in[1];
    const float* proj1_b   = (const float*)d_in[2];
    const float* conv0_w   = (const float*)d_in[3];
    const float* conv0_b   = (const float*)d_in[4];
    const float* inproj_w  = (const float*)d_in[5];
    const float* inproj_b  = (const float*)d_in[6];
    const float* dw_w      = (const float*)d_in[7];
    const float* dw_b      = (const float*)d_in[8];
    const float* ln_g      = (const float*)d_in[9];
    const float* ln_b      = (const float*)d_in[10];
    const float* off_w     = (const float*)d_in[11];
    const float* off_b     = (const float*)d_in[12];
    const float* mask_w    = (const float*)d_in[13];
    const float* mask_b    = (const float*)d_in[14];
    const float* outproj_w = (const float*)d_in[15];
    const float* outproj_b = (const float*)d_in[16];
    const float* conv_w    = (const float*)d_in[17];
    const float* conv_b    = (const float*)d_in[18];
    const float* proj2_w   = (const float*)d_in[19];
    const float* proj2_b   = (const float*)d_in[20];
    float* outp = (float*)d_out;

    const size_t NC = (size_t)NPIX * CCH;
    float* b0 = (float*)d_ws;      // x_t -> x1 -> dcnout
    float* b1 = b0 + NC;           // u (persists to the end)
    float* b2 = b1 + NC;           // h5 -> offset/mask -> attn2
    float* b3 = outp;              // d_out as scratch: wT/wT3 -> xproj -> attn -> final
    float* wT  = b3;               // 25x256 floats
    float* wT3 = b3 + 25 * CCH;    // 9x256 floats (dead before xproj overwrites)

    // 0. transpose depthwise weights (lives in d_out head until dw3 done)
    k_prep<<<1,256,0,stream>>>(conv0_w, dw_w, wT, wT3);
    // 1. x (NCHW) -> NHWC
    k_transpose<<<dim3(64,4,4),256,0,stream>>>(x, b0);
    // 2. u = gelu(x @ proj1_w + b)
    k_gemm<1,false><<<dim3(128,2),256,0,stream>>>(b0, nullptr, proj1_w, proj1_b, nullptr, b1, 256, 256);
    // 3. h5 = dwconv5x5(u)
    k_dwconv5<<<4096,256,0,stream>>>(b1, wT, conv0_b, b2);
    // 4. x1 = gelu(LN(dwconv3x3(h5)))  (before inproj so wT3 in d_out stays alive)
    k_dw3_ln_gelu<<<4096,256,0,stream>>>(b2, wT3, dw_b, ln_g, ln_b, b0);
    // 5. xproj = h5 @ inproj_w + b  -> d_out scratch
    k_gemm<0,false><<<dim3(128,2),256,0,stream>>>(b2, nullptr, inproj_w, inproj_b, nullptr, b3, 256, 256);
    // 6. offset cols [0,144) and mask logits cols [144,216) into b2 (ld 216)
    k_gemm<0,false><<<dim3(128,2),256,0,stream>>>(b0, nullptr, off_w,  off_b,  nullptr, b2,       144, 216);
    k_gemm<0,false><<<dim3(128,1),256,0,stream>>>(b0, nullptr, mask_w, mask_b, nullptr, b2 + 144,  72, 216);
    // 7. DCN core (softmax fused)
    k_dcn<<<4096,256,0,stream>>>(b3, b2, b0);
    // 8. attn = dcnout @ outproj_w + b
    k_gemm<0,false><<<dim3(128,2),256,0,stream>>>(b0, nullptr, outproj_w, outproj_b, nullptr, b3, 256, 256);
    // 9. attn2 = attn @ conv_w + b
    k_gemm<0,false><<<dim3(128,2),256,0,stream>>>(b3, nullptr, conv_w, conv_b, nullptr, b2, 256, 256);
    // 10. out = (u * attn2) @ proj2_w + b + x   (NCHW write, fused residual)
    k_gemm<2,true><<<dim3(128,2),256,0,stream>>>(b1, b2, proj2_w, proj2_b, x, outp, 256, 256);
}

// Round 5
// 472.531 us; speedup vs baseline: 1.4653x; 1.0299x over previous
//
#include <hip/hip_runtime.h>
#include <cstddef>

#define HW    4096
#define NPIX  16384
#define CCH   256

typedef __attribute__((ext_vector_type(8))) short bf16x8;
typedef __attribute__((ext_vector_type(4))) float f32x4;

__device__ __forceinline__ float gelu_f(float x){
    return 0.5f * x * (1.0f + erff(x * 0.70710678118654752f));
}

__device__ __forceinline__ unsigned short bf_rne(float f){
    unsigned u = __float_as_uint(f);
    u += 0x7FFFu + ((u >> 16) & 1u);
    return (unsigned short)(u >> 16);
}

// split fp32 -> bf16 hi (trunc) + lo (RNE of remainder); hi+lo carries ~16 mantissa bits
__device__ __forceinline__ void split2(const float4 a, const float4 b, bf16x8& hi, bf16x8& lo){
    const float v[8] = {a.x,a.y,a.z,a.w,b.x,b.y,b.z,b.w};
    #pragma unroll
    for (int j = 0; j < 8; j++){
        const unsigned u = __float_as_uint(v[j]);
        hi[j] = (short)(unsigned short)(u >> 16);
        lo[j] = (short)bf_rne(v[j] - __uint_as_float(u & 0xFFFF0000u));
    }
}

// ---------------- conv-weight transpose prep: w5 (256x25)->wT (25x256); w3 (256x9)->wT3 ----
__global__ __launch_bounds__(256) void k_prep(const float* __restrict__ w5,
                                              const float* __restrict__ w3,
                                              float* __restrict__ wT,
                                              float* __restrict__ wT3){
    const int c = threadIdx.x;
    #pragma unroll
    for (int k = 0; k < 25; k++) wT[k * CCH + c] = w5[c * 25 + k];
    #pragma unroll
    for (int k = 0; k < 9;  k++) wT3[k * CCH + c] = w3[c * 9 + k];
}

// ---------------- GEMM-weight prep: W[k][m] fp32 -> W_T[m][k] bf16 hi/lo --------------------
// ids 0..4: square 256x256 weights; id 5: concat(off_w 256x144, mask_w 256x72, zero-pad to 256)
__global__ __launch_bounds__(256) void k_prep_w(
    const float* __restrict__ w0, const float* __restrict__ w1, const float* __restrict__ w2,
    const float* __restrict__ w3, const float* __restrict__ w4,
    const float* __restrict__ offw, const float* __restrict__ maskw,
    const float* __restrict__ offb, const float* __restrict__ maskb,
    unsigned short* __restrict__ wsp, float* __restrict__ bcat)
{
    const int id = blockIdx.x, n = threadIdx.x;
    unsigned short* hi = wsp + (size_t)id * 131072;
    unsigned short* lo = hi + 65536;
    if (id == 5){
        for (int k = 0; k < 256; k++){
            const float f = (n < 144) ? offw[k*144 + n]
                          : (n < 216) ? maskw[k*72 + (n - 144)] : 0.f;
            const unsigned u = __float_as_uint(f);
            hi[n*256 + k] = (unsigned short)(u >> 16);
            lo[n*256 + k] = bf_rne(f - __uint_as_float(u & 0xFFFF0000u));
        }
        if (n < 216) bcat[n] = (n < 144) ? offb[n] : maskb[n - 144];
        else if (n < 224) bcat[n] = 0.f;
    } else {
        const float* s = (id==0)?w0:(id==1)?w1:(id==2)?w2:(id==3)?w3:w4;
        for (int k = 0; k < 256; k++){
            const float f = s[k*256 + n];
            const unsigned u = __float_as_uint(f);
            hi[n*256 + k] = (unsigned short)(u >> 16);
            lo[n*256 + k] = bf_rne(f - __uint_as_float(u & 0xFFFF0000u));
        }
    }
}

// ---------------- transpose NCHW -> NHWC ----------------
__global__ __launch_bounds__(256) void k_transpose(const float* __restrict__ in,
                                                   float* __restrict__ out){
    __shared__ float tile[64][65];
    const int b = blockIdx.z, c0 = blockIdx.y * 64, hw0 = blockIdx.x * 64;
    const int tx = threadIdx.x & 63, tg = threadIdx.x >> 6;
    #pragma unroll
    for (int i = 0; i < 16; i++){
        const int c_l = tg * 16 + i;
        tile[c_l][tx] = in[(size_t)(b * CCH + c0 + c_l) * HW + hw0 + tx];
    }
    __syncthreads();
    #pragma unroll
    for (int i = 0; i < 16; i++){
        const int hw_l = tg * 16 + i;
        out[(size_t)(b * HW + hw0 + hw_l) * CCH + c0 + tx] = tile[tx][hw_l];
    }
}

// ---------------- bf16 split-3 MFMA GEMM: out(16384 x M) = A(16384 x 256) @ W(256 x M) ------
// A: fp32, split in-register. W: pre-split bf16 hi/lo, transposed [m][k].
// Tile 64(rows) x 128(cols), 4 waves in 2x2 quadrants of 32x64.
// Frag layouts (verified m89/m97): A/B in: idx=lane&15, k=8*(lane>>4)+j ; C/D: col=lane&15, row=4*(lane>>4)+reg
// EPI: 0 = bias, 1 = bias+gelu, 2 = bias + residual + NCHW write. MUL: A *= A2 elementwise.
template<int EPI, bool MUL>
__global__ __launch_bounds__(256) void k_gemm_bf(
    const float* __restrict__ A, const float* __restrict__ A2,
    const unsigned short* __restrict__ Whi, const unsigned short* __restrict__ Wlo,
    const float* __restrict__ bias, const float* __restrict__ resid,
    float* __restrict__ out, const int M, const int ldc)
{
    const int rows0 = blockIdx.x * 64;
    const int cols0 = blockIdx.y * 128;
    const int lane = threadIdx.x & 63;
    const int w    = threadIdx.x >> 6;
    const int wm = (w >> 1) * 32, wn = (w & 1) * 64;
    const int lr = lane & 15;
    const int kg = lane >> 4;
    const int kl = kg * 8;

    const float* A0 = A + (size_t)(rows0 + wm + lr) * 256 + kl;
    const float* A1 = A0 + 16 * 256;
    const float* M0 = MUL ? (A2 + (size_t)(rows0 + wm + lr) * 256 + kl) : nullptr;
    const float* M1 = MUL ? (M0 + 16 * 256) : nullptr;
    const int c0 = cols0 + wn + lr;
    const unsigned short* Wh = Whi + (size_t)c0 * 256 + kl;
    const unsigned short* Wl = Wlo + (size_t)c0 * 256 + kl;

    const f32x4 z = {0.f, 0.f, 0.f, 0.f};
    f32x4 acc[2][4] = {{z,z,z,z},{z,z,z,z}};

    #pragma unroll 2
    for (int kt = 0; kt < 8; kt++){
        const int k0 = kt * 32;
        float4 a0 = *reinterpret_cast<const float4*>(A0 + k0);
        float4 a1 = *reinterpret_cast<const float4*>(A0 + k0 + 4);
        float4 a2 = *reinterpret_cast<const float4*>(A1 + k0);
        float4 a3 = *reinterpret_cast<const float4*>(A1 + k0 + 4);
        if (MUL){
            const float4 u0 = *reinterpret_cast<const float4*>(M0 + k0);
            const float4 u1 = *reinterpret_cast<const float4*>(M0 + k0 + 4);
            const float4 u2 = *reinterpret_cast<const float4*>(M1 + k0);
            const float4 u3 = *reinterpret_cast<const float4*>(M1 + k0 + 4);
            a0.x*=u0.x; a0.y*=u0.y; a0.z*=u0.z; a0.w*=u0.w;
            a1.x*=u1.x; a1.y*=u1.y; a1.z*=u1.z; a1.w*=u1.w;
            a2.x*=u2.x; a2.y*=u2.y; a2.z*=u2.z; a2.w*=u2.w;
            a3.x*=u3.x; a3.y*=u3.y; a3.z*=u3.z; a3.w*=u3.w;
        }
        bf16x8 ah0, al0, ah1, al1;
        split2(a0, a1, ah0, al0);
        split2(a2, a3, ah1, al1);
        #pragma unroll
        for (int nf = 0; nf < 4; nf++){
            const size_t wo = (size_t)(nf * 16) * 256 + k0;
            const bf16x8 bh = *reinterpret_cast<const bf16x8*>(Wh + wo);
            const bf16x8 bl = *reinterpret_cast<const bf16x8*>(Wl + wo);
            acc[0][nf] = __builtin_amdgcn_mfma_f32_16x16x32_bf16(ah0, bh, acc[0][nf], 0, 0, 0);
            acc[0][nf] = __builtin_amdgcn_mfma_f32_16x16x32_bf16(ah0, bl, acc[0][nf], 0, 0, 0);
            acc[0][nf] = __builtin_amdgcn_mfma_f32_16x16x32_bf16(al0, bh, acc[0][nf], 0, 0, 0);
            acc[1][nf] = __builtin_amdgcn_mfma_f32_16x16x32_bf16(ah1, bh, acc[1][nf], 0, 0, 0);
            acc[1][nf] = __builtin_amdgcn_mfma_f32_16x16x32_bf16(ah1, bl, acc[1][nf], 0, 0, 0);
            acc[1][nf] = __builtin_amdgcn_mfma_f32_16x16x32_bf16(al1, bh, acc[1][nf], 0, 0, 0);
        }
    }

    const int r4 = kg * 4;
    if (EPI == 2){
        #pragma unroll
        for (int nf = 0; nf < 4; nf++){
            const int col = c0 + nf * 16;
            const float bs = bias[col];
            #pragma unroll
            for (int mf = 0; mf < 2; mf++){
                const int row = rows0 + wm + mf * 16 + r4;
                const int bimg = row >> 12;
                const int hw = row & (HW - 1);
                const size_t addr = ((size_t)(bimg * CCH + col)) * HW + hw;
                const float4 rv = *reinterpret_cast<const float4*>(resid + addr);
                float4 o;
                o.x = acc[mf][nf][0] + bs + rv.x;
                o.y = acc[mf][nf][1] + bs + rv.y;
                o.z = acc[mf][nf][2] + bs + rv.z;
                o.w = acc[mf][nf][3] + bs + rv.w;
                *reinterpret_cast<float4*>(out + addr) = o;
            }
        }
    } else {
        #pragma unroll
        for (int nf = 0; nf < 4; nf++){
            const int col = c0 + nf * 16;
            if (col < M){
                const float bs = bias[col];
                #pragma unroll
                for (int mf = 0; mf < 2; mf++){
                    const int rowb = rows0 + wm + mf * 16 + r4;
                    #pragma unroll
                    for (int r = 0; r < 4; r++){
                        float v = acc[mf][nf][r] + bs;
                        if (EPI == 1) v = gelu_f(v);
                        out[(size_t)(rowb + r) * ldc + col] = v;
                    }
                }
            }
        }
    }
}

// ---------------- depthwise 5x5, pad 2, NHWC — branchless, float4 channels ----------------
__global__ __launch_bounds__(256) void k_dwconv5(const float* __restrict__ in,
                                                 const float* __restrict__ wT,
                                                 const float* __restrict__ bias,
                                                 float* __restrict__ out){
    const int lane = threadIdx.x & 63;
    const int pq   = threadIdx.x >> 6;
    const int n = blockIdx.x * 4 + pq;
    const int x = n & 63, y = (n >> 6) & 63, b = n >> 12;
    const int c = lane * 4;
    const float* bp = in + (size_t)(b * HW) * CCH + c;
    float4 acc = *reinterpret_cast<const float4*>(bias + c);
    #pragma unroll
    for (int k = 0; k < 25; k++){
        const int dy = k / 5 - 2, dx = k % 5 - 2;
        const int yy = y + dy, xx = x + dx;
        const float m = (((unsigned)yy < 64u) & ((unsigned)xx < 64u)) ? 1.f : 0.f;
        const int yc = min(max(yy, 0), 63), xc = min(max(xx, 0), 63);
        const float4 iv = *reinterpret_cast<const float4*>(bp + (size_t)(yc * 64 + xc) * CCH);
        const float4 wv = *reinterpret_cast<const float4*>(wT + k * CCH + c);
        acc.x = fmaf(iv.x, wv.x * m, acc.x);
        acc.y = fmaf(iv.y, wv.y * m, acc.y);
        acc.z = fmaf(iv.z, wv.z * m, acc.z);
        acc.w = fmaf(iv.w, wv.w * m, acc.w);
    }
    *reinterpret_cast<float4*>(out + (size_t)n * CCH + c) = acc;
}

// ---------------- depthwise 3x3 + LayerNorm(channel) + GELU — branchless, wave-reduce ------
__global__ __launch_bounds__(256) void k_dw3_ln_gelu(const float* __restrict__ in,
                                                     const float* __restrict__ wT3,
                                                     const float* __restrict__ b3,
                                                     const float* __restrict__ g,
                                                     const float* __restrict__ bta,
                                                     float* __restrict__ out){
    const int lane = threadIdx.x & 63;
    const int pq   = threadIdx.x >> 6;
    const int n = blockIdx.x * 4 + pq;
    const int x = n & 63, y = (n >> 6) & 63, b = n >> 12;
    const int c = lane * 4;
    const float* bp = in + (size_t)(b * HW) * CCH + c;
    float4 acc = *reinterpret_cast<const float4*>(b3 + c);
    #pragma unroll
    for (int k = 0; k < 9; k++){
        const int dy = k / 3 - 1, dx = k % 3 - 1;
        const int yy = y + dy, xx = x + dx;
        const float m = (((unsigned)yy < 64u) & ((unsigned)xx < 64u)) ? 1.f : 0.f;
        const int yc = min(max(yy, 0), 63), xc = min(max(xx, 0), 63);
        const float4 iv = *reinterpret_cast<const float4*>(bp + (size_t)(yc * 64 + xc) * CCH);
        const float4 wv = *reinterpret_cast<const float4*>(wT3 + k * CCH + c);
        acc.x = fmaf(iv.x, wv.x * m, acc.x);
        acc.y = fmaf(iv.y, wv.y * m, acc.y);
        acc.z = fmaf(iv.z, wv.z * m, acc.z);
        acc.w = fmaf(iv.w, wv.w * m, acc.w);
    }
    float s  = acc.x + acc.y + acc.z + acc.w;
    float s2 = acc.x*acc.x + acc.y*acc.y + acc.z*acc.z + acc.w*acc.w;
    #pragma unroll
    for (int o = 32; o > 0; o >>= 1){
        s  += __shfl_xor(s, o);
        s2 += __shfl_xor(s2, o);
    }
    const float mu  = s  * (1.f / 256.f);
    const float var = s2 * (1.f / 256.f) - mu * mu;
    const float r   = rsqrtf(var + 1e-5f);
    const float4 gv = *reinterpret_cast<const float4*>(g + c);
    const float4 bv = *reinterpret_cast<const float4*>(bta + c);
    float4 o;
    o.x = gelu_f((acc.x - mu) * r * gv.x + bv.x);
    o.y = gelu_f((acc.y - mu) * r * gv.y + bv.y);
    o.z = gelu_f((acc.z - mu) * r * gv.z + bv.z);
    o.w = gelu_f((acc.w - mu) * r * gv.w + bv.w);
    *reinterpret_cast<float4*>(out + (size_t)n * CCH + c) = o;
}

// ---------------- DCNv3 core: fused softmax + bilinear sample + mask-weighted sum ----------
__global__ __launch_bounds__(256) void k_dcn(const float* __restrict__ xproj,
                                             const float* __restrict__ om,
                                             float* __restrict__ out){
    const int lane = threadIdx.x & 63;
    const int pq   = threadIdx.x >> 6;
    const int n = blockIdx.x * 4 + pq;
    const int gI = lane >> 3, cq = lane & 7;
    const int x = n & 63, y = (n >> 6) & 63, b = n >> 12;
    const float* off = om + (size_t)n * 216 + gI * 18;
    const float* lg  = om + (size_t)n * 216 + 144 + gI * 9;
    float l[9]; float mx = -1e30f;
    #pragma unroll
    for (int p = 0; p < 9; p++){ l[p] = lg[p]; mx = fmaxf(mx, l[p]); }
    float ssum = 0.f;
    #pragma unroll
    for (int p = 0; p < 9; p++){ l[p] = expf(l[p] - mx); ssum += l[p]; }
    const float inv = 1.f / ssum;
    const float* base = xproj + (size_t)b * HW * CCH + gI * 32 + cq * 4;
    float4 acc = {0.f, 0.f, 0.f, 0.f};
    #pragma unroll
    for (int p = 0; p < 9; p++){
        const float2 o2 = *reinterpret_cast<const float2*>(off + p * 2);
        const float ix = (float)(x + p / 3) + o2.x;
        const float iy = (float)(y + p % 3) + o2.y;
        const float x0f = floorf(ix), y0f = floorf(iy);
        const float wx1 = ix - x0f, wy1 = iy - y0f;
        const float wx0 = 1.f - wx1, wy0 = 1.f - wy1;
        const int ux = (int)x0f - 1, uy = (int)y0f - 1;
        const bool X0 = (unsigned)ux     < 64u, X1 = (unsigned)(ux+1) < 64u;
        const bool Y0 = (unsigned)uy     < 64u, Y1 = (unsigned)(uy+1) < 64u;
        const int ux0 = min(max(ux,     0), 63), ux1 = min(max(ux + 1, 0), 63);
        const int uy0 = min(max(uy,     0), 63), uy1 = min(max(uy + 1, 0), 63);
        const float mp = l[p] * inv;
        const float w00 = wx0 * wy0 * ((X0 & Y0) ? mp : 0.f);
        const float w01 = wx1 * wy0 * ((X1 & Y0) ? mp : 0.f);
        const float w10 = wx0 * wy1 * ((X0 & Y1) ? mp : 0.f);
        const float w11 = wx1 * wy1 * ((X1 & Y1) ? mp : 0.f);
        const float4 v00 = *reinterpret_cast<const float4*>(base + (size_t)(uy0 * 64 + ux0) * CCH);
        const float4 v01 = *reinterpret_cast<const float4*>(base + (size_t)(uy0 * 64 + ux1) * CCH);
        const float4 v10 = *reinterpret_cast<const float4*>(base + (size_t)(uy1 * 64 + ux0) * CCH);
        const float4 v11 = *reinterpret_cast<const float4*>(base + (size_t)(uy1 * 64 + ux1) * CCH);
        acc.x = fmaf(w00, v00.x, fmaf(w01, v01.x, fmaf(w10, v10.x, fmaf(w11, v11.x, acc.x))));
        acc.y = fmaf(w00, v00.y, fmaf(w01, v01.y, fmaf(w10, v10.y, fmaf(w11, v11.y, acc.y))));
        acc.z = fmaf(w00, v00.z, fmaf(w01, v01.z, fmaf(w10, v10.z, fmaf(w11, v11.z, acc.z))));
        acc.w = fmaf(w00, v00.w, fmaf(w01, v01.w, fmaf(w10, v10.w, fmaf(w11, v11.w, acc.w))));
    }
    *reinterpret_cast<float4*>(out + (size_t)n * CCH + gI * 32 + cq * 4) = acc;
}

extern "C" void kernel_launch(void* const* d_in, const int* in_sizes, int n_in,
                              void* d_out, int out_size, void* d_ws, size_t ws_size,
                              hipStream_t stream){
    const float* x         = (const float*)d_in[0];
    const float* proj1_w   = (const float*)d_in[1];
    const float* proj1_b   = (const float*)d_in[2];
    const float* conv0_w   = (const float*)d_in[3];
    const float* conv0_b   = (const float*)d_in[4];
    const float* inproj_w  = (const float*)d_in[5];
    const float* inproj_b  = (const float*)d_in[6];
    const float* dw_w      = (const float*)d_in[7];
    const float* dw_b      = (const float*)d_in[8];
    const float* ln_g      = (const float*)d_in[9];
    const float* ln_b      = (const float*)d_in[10];
    const float* off_w     = (const float*)d_in[11];
    const float* off_b     = (const float*)d_in[12];
    const float* mask_w    = (const float*)d_in[13];
    const float* mask_b    = (const float*)d_in[14];
    const float* outproj_w = (const float*)d_in[15];
    const float* outproj_b = (const float*)d_in[16];
    const float* conv_w    = (const float*)d_in[17];
    const float* conv_b    = (const float*)d_in[18];
    const float* proj2_w   = (const float*)d_in[19];
    const float* proj2_b   = (const float*)d_in[20];
    float* outp = (float*)d_out;

    const size_t NC = (size_t)NPIX * CCH;
    float* b0 = (float*)d_ws;      // x_t -> x1 -> dcnout
    float* b1 = b0 + NC;           // u (persists to the end)
    float* b2 = b1 + NC;           // h5 -> offset/mask(om) -> attn2
    float* b3 = outp;              // d_out as scratch: conv-wT -> xproj -> attn -> final
    unsigned short* wsp = (unsigned short*)(b2 + NC);   // 6 pairs of 256x256 bf16 hi/lo
    float* bcat = (float*)(wsp + 6 * 131072);           // 224 floats (off_b ++ mask_b ++ 0)
    float* wT   = b3;              // 25x256 conv5 weights (dead before xproj)
    float* wT3  = b3 + 25 * CCH;   // 9x256 conv3 weights

    const unsigned short* whi[6]; const unsigned short* wlo[6];
    for (int i = 0; i < 6; i++){ whi[i] = wsp + (size_t)i * 131072; wlo[i] = whi[i] + 65536; }

    const dim3 G(256, 2);

    // 0. weight preps
    k_prep<<<1,256,0,stream>>>(conv0_w, dw_w, wT, wT3);
    k_prep_w<<<6,256,0,stream>>>(proj1_w, inproj_w, outproj_w, conv_w, proj2_w,
                                 off_w, mask_w, off_b, mask_b, wsp, bcat);
    // 1. x (NCHW) -> NHWC
    k_transpose<<<dim3(64,4,4),256,0,stream>>>(x, b0);
    // 2. u = gelu(x @ proj1_w + b)
    k_gemm_bf<1,false><<<G,256,0,stream>>>(b0, nullptr, whi[0], wlo[0], proj1_b, nullptr, b1, 256, 256);
    // 3. h5 = dwconv5x5(u)
    k_dwconv5<<<4096,256,0,stream>>>(b1, wT, conv0_b, b2);
    // 4. x1 = gelu(LN(dwconv3x3(h5)))  (before xproj overwrites d_out head)
    k_dw3_ln_gelu<<<4096,256,0,stream>>>(b2, wT3, dw_b, ln_g, ln_b, b0);
    // 5. xproj = h5 @ inproj_w + b  -> d_out scratch
    k_gemm_bf<0,false><<<G,256,0,stream>>>(b2, nullptr, whi[1], wlo[1], inproj_b, nullptr, b3, 256, 256);
    // 6. offset||mask logits = x1 @ [off_w|mask_w] + b  (M=216, ld 216) into b2
    k_gemm_bf<0,false><<<G,256,0,stream>>>(b0, nullptr, whi[5], wlo[5], bcat, nullptr, b2, 216, 216);
    // 7. DCN core (softmax fused)
    k_dcn<<<4096,256,0,stream>>>(b3, b2, b0);
    // 8. attn = dcnout @ outproj_w + b
    k_gemm_bf<0,false><<<G,256,0,stream>>>(b0, nullptr, whi[2], wlo[2], outproj_b, nullptr, b3, 256, 256);
    // 9. attn2 = attn @ conv_w + b
    k_gemm_bf<0,false><<<G,256,0,stream>>>(b3, nullptr, whi[3], wlo[3], conv_b, nullptr, b2, 256, 256);
    // 10. out = (u * attn2) @ proj2_w + b + x   (NCHW write, fused residual)
    k_gemm_bf<2,true><<<G,256,0,stream>>>(b1, b2, whi[4], wlo[4], proj2_b, x, outp, 256, 256);
}

// Round 8
// 359.231 us; speedup vs baseline: 1.9275x; 1.3154x over previous
//
#include <hip/hip_runtime.h>
#include <cstddef>

#define HW    4096
#define NPIX  16384
#define CCH   256

typedef __attribute__((ext_vector_type(8))) short bf16x8;
typedef __attribute__((ext_vector_type(4))) float f32x4;

__device__ __forceinline__ float gelu_f(float x){
    return 0.5f * x * (1.0f + erff(x * 0.70710678118654752f));
}

__device__ __forceinline__ unsigned short bf_rne(float f){
    unsigned u = __float_as_uint(f);
    u += 0x7FFFu + ((u >> 16) & 1u);
    return (unsigned short)(u >> 16);
}

// split fp32 -> bf16 hi (trunc) + lo (RNE of remainder); hi+lo carries ~16 mantissa bits
__device__ __forceinline__ void split2(const float4 a, const float4 b, bf16x8& hi, bf16x8& lo){
    const float v[8] = {a.x,a.y,a.z,a.w,b.x,b.y,b.z,b.w};
    #pragma unroll
    for (int j = 0; j < 8; j++){
        const unsigned u = __float_as_uint(v[j]);
        hi[j] = (short)(unsigned short)(u >> 16);
        lo[j] = (short)bf_rne(v[j] - __uint_as_float(u & 0xFFFF0000u));
    }
}

// ---------------- conv-weight transpose: one tap per block ----------------
__global__ __launch_bounds__(256) void k_prep(const float* __restrict__ w5,
                                              const float* __restrict__ w3,
                                              float* __restrict__ wT,
                                              float* __restrict__ wT3){
    const int c = threadIdx.x;
    const int j = blockIdx.x;
    wT[j * CCH + c] = w5[c * 25 + j];
    if (j < 9) wT3[j * CCH + c] = w3[c * 9 + j];
}

// ---------------- GEMM-weight prep: W[k][m] fp32 -> W_T[m][k] bf16 hi/lo, LDS-tiled ---------
// grid (16, 6): blockIdx.y = matrix id (0..4 square weights, 5 = off||mask concat),
// blockIdx.x = 64x64 tile (m-tile = bx&3, k-tile = bx>>2)
__global__ __launch_bounds__(256) void k_prep_w(
    const float* __restrict__ w0, const float* __restrict__ w1, const float* __restrict__ w2,
    const float* __restrict__ w3, const float* __restrict__ w4,
    const float* __restrict__ offw, const float* __restrict__ maskw,
    const float* __restrict__ offb, const float* __restrict__ maskb,
    unsigned short* __restrict__ wsp, float* __restrict__ bcat)
{
    __shared__ float tile[64][65];
    const int id = blockIdx.y;
    const int m0 = (blockIdx.x & 3) * 64;
    const int k0 = (blockIdx.x >> 2) * 64;
    const int tx = threadIdx.x & 63, tg = threadIdx.x >> 6;
    unsigned short* hi = wsp + (size_t)id * 131072;
    unsigned short* lo = hi + 65536;

    // column m = m0+tx selects the source pointer/stride (uniform per thread)
    const int m = m0 + tx;
    const float* src = nullptr; int stride = 0; bool valid = true;
    if (id == 5){
        if (m < 144){ src = offw + m; stride = 144; }
        else if (m < 216){ src = maskw + (m - 144); stride = 72; }
        else valid = false;
    } else {
        const float* s = (id==0)?w0:(id==1)?w1:(id==2)?w2:(id==3)?w3:w4;
        src = s + m; stride = 256;
    }
    #pragma unroll
    for (int i = 0; i < 16; i++){
        const int kl = tg * 16 + i;
        tile[kl][tx] = valid ? src[(size_t)(k0 + kl) * stride] : 0.f;
    }
    __syncthreads();
    #pragma unroll
    for (int i = 0; i < 16; i++){
        const int ml = tg * 16 + i;
        const float f = tile[tx][ml];
        const unsigned u = __float_as_uint(f);
        const size_t o = (size_t)(m0 + ml) * 256 + k0 + tx;
        hi[o] = (unsigned short)(u >> 16);
        lo[o] = bf_rne(f - __uint_as_float(u & 0xFFFF0000u));
    }
    if (id == 5 && blockIdx.x == 0){
        const int t = threadIdx.x;
        if (t < 216) bcat[t] = (t < 144) ? offb[t] : maskb[t - 144];
        else if (t < 224) bcat[t] = 0.f;
    }
}

// ---------------- transpose NCHW -> NHWC ----------------
__global__ __launch_bounds__(256) void k_transpose(const float* __restrict__ in,
                                                   float* __restrict__ out){
    __shared__ float tile[64][65];
    const int b = blockIdx.z, c0 = blockIdx.y * 64, hw0 = blockIdx.x * 64;
    const int tx = threadIdx.x & 63, tg = threadIdx.x >> 6;
    #pragma unroll
    for (int i = 0; i < 16; i++){
        const int c_l = tg * 16 + i;
        tile[c_l][tx] = in[(size_t)(b * CCH + c0 + c_l) * HW + hw0 + tx];
    }
    __syncthreads();
    #pragma unroll
    for (int i = 0; i < 16; i++){
        const int hw_l = tg * 16 + i;
        out[(size_t)(b * HW + hw0 + hw_l) * CCH + c0 + tx] = tile[tx][hw_l];
    }
}

// ---------------- bf16 split-3 MFMA GEMM: out(16384 x M) = A(16384 x 256) @ W(256 x M) ------
// A: fp32, split in-register. W: pre-split bf16 hi/lo, transposed [m][k].
// Tile 64(rows) x 128(cols), 4 waves in 2x2 quadrants of 32x64.
// Frag layouts (verified m89/m97): A/B in: idx=lane&15, k=8*(lane>>4)+j ; C/D: col=lane&15, row=4*(lane>>4)+reg
// EPI: 0 = bias, 1 = bias+gelu, 2 = bias + residual + NCHW write. MUL: A *= A2 elementwise.
template<int EPI, bool MUL>
__global__ __launch_bounds__(256) void k_gemm_bf(
    const float* __restrict__ A, const float* __restrict__ A2,
    const unsigned short* __restrict__ Whi, const unsigned short* __restrict__ Wlo,
    const float* __restrict__ bias, const float* __restrict__ resid,
    float* __restrict__ out, const int M, const int ldc)
{
    const int rows0 = blockIdx.x * 64;
    const int cols0 = blockIdx.y * 128;
    const int lane = threadIdx.x & 63;
    const int w    = threadIdx.x >> 6;
    const int wm = (w >> 1) * 32, wn = (w & 1) * 64;
    const int lr = lane & 15;
    const int kg = lane >> 4;
    const int kl = kg * 8;

    const float* A0 = A + (size_t)(rows0 + wm + lr) * 256 + kl;
    const float* A1 = A0 + 16 * 256;
    const float* M0 = MUL ? (A2 + (size_t)(rows0 + wm + lr) * 256 + kl) : nullptr;
    const float* M1 = MUL ? (M0 + 16 * 256) : nullptr;
    const int c0 = cols0 + wn + lr;
    const unsigned short* Wh = Whi + (size_t)c0 * 256 + kl;
    const unsigned short* Wl = Wlo + (size_t)c0 * 256 + kl;

    const f32x4 z = {0.f, 0.f, 0.f, 0.f};
    f32x4 acc[2][4] = {{z,z,z,z},{z,z,z,z}};

    #pragma unroll 2
    for (int kt = 0; kt < 8; kt++){
        const int k0 = kt * 32;
        float4 a0 = *reinterpret_cast<const float4*>(A0 + k0);
        float4 a1 = *reinterpret_cast<const float4*>(A0 + k0 + 4);
        float4 a2 = *reinterpret_cast<const float4*>(A1 + k0);
        float4 a3 = *reinterpret_cast<const float4*>(A1 + k0 + 4);
        if (MUL){
            const float4 u0 = *reinterpret_cast<const float4*>(M0 + k0);
            const float4 u1 = *reinterpret_cast<const float4*>(M0 + k0 + 4);
            const float4 u2 = *reinterpret_cast<const float4*>(M1 + k0);
            const float4 u3 = *reinterpret_cast<const float4*>(M1 + k0 + 4);
            a0.x*=u0.x; a0.y*=u0.y; a0.z*=u0.z; a0.w*=u0.w;
            a1.x*=u1.x; a1.y*=u1.y; a1.z*=u1.z; a1.w*=u1.w;
            a2.x*=u2.x; a2.y*=u2.y; a2.z*=u2.z; a2.w*=u2.w;
            a3.x*=u3.x; a3.y*=u3.y; a3.z*=u3.z; a3.w*=u3.w;
        }
        bf16x8 ah0, al0, ah1, al1;
        split2(a0, a1, ah0, al0);
        split2(a2, a3, ah1, al1);
        #pragma unroll
        for (int nf = 0; nf < 4; nf++){
            const size_t wo = (size_t)(nf * 16) * 256 + k0;
            const bf16x8 bh = *reinterpret_cast<const bf16x8*>(Wh + wo);
            const bf16x8 bl = *reinterpret_cast<const bf16x8*>(Wl + wo);
            acc[0][nf] = __builtin_amdgcn_mfma_f32_16x16x32_bf16(ah0, bh, acc[0][nf], 0, 0, 0);
            acc[0][nf] = __builtin_amdgcn_mfma_f32_16x16x32_bf16(ah0, bl, acc[0][nf], 0, 0, 0);
            acc[0][nf] = __builtin_amdgcn_mfma_f32_16x16x32_bf16(al0, bh, acc[0][nf], 0, 0, 0);
            acc[1][nf] = __builtin_amdgcn_mfma_f32_16x16x32_bf16(ah1, bh, acc[1][nf], 0, 0, 0);
            acc[1][nf] = __builtin_amdgcn_mfma_f32_16x16x32_bf16(ah1, bl, acc[1][nf], 0, 0, 0);
            acc[1][nf] = __builtin_amdgcn_mfma_f32_16x16x32_bf16(al1, bh, acc[1][nf], 0, 0, 0);
        }
    }

    const int r4 = kg * 4;
    if (EPI == 2){
        #pragma unroll
        for (int nf = 0; nf < 4; nf++){
            const int col = c0 + nf * 16;
            const float bs = bias[col];
            #pragma unroll
            for (int mf = 0; mf < 2; mf++){
                const int row = rows0 + wm + mf * 16 + r4;
                const int bimg = row >> 12;
                const int hw = row & (HW - 1);
                const size_t addr = ((size_t)(bimg * CCH + col)) * HW + hw;
                const float4 rv = *reinterpret_cast<const float4*>(resid + addr);
                float4 o;
                o.x = acc[mf][nf][0] + bs + rv.x;
                o.y = acc[mf][nf][1] + bs + rv.y;
                o.z = acc[mf][nf][2] + bs + rv.z;
                o.w = acc[mf][nf][3] + bs + rv.w;
                *reinterpret_cast<float4*>(out + addr) = o;
            }
        }
    } else {
        #pragma unroll
        for (int nf = 0; nf < 4; nf++){
            const int col = c0 + nf * 16;
            if (col < M){
                const float bs = bias[col];
                #pragma unroll
                for (int mf = 0; mf < 2; mf++){
                    const int rowb = rows0 + wm + mf * 16 + r4;
                    #pragma unroll
                    for (int r = 0; r < 4; r++){
                        float v = acc[mf][nf][r] + bs;
                        if (EPI == 1) v = gelu_f(v);
                        out[(size_t)(rowb + r) * ldc + col] = v;
                    }
                }
            }
        }
    }
}

// ---------------- depthwise 5x5, pad 2, NHWC — branchless, float4 channels ----------------
__global__ __launch_bounds__(256) void k_dwconv5(const float* __restrict__ in,
                                                 const float* __restrict__ wT,
                                                 const float* __restrict__ bias,
                                                 float* __restrict__ out){
    const int lane = threadIdx.x & 63;
    const int pq   = threadIdx.x >> 6;
    const int n = blockIdx.x * 4 + pq;
    const int x = n & 63, y = (n >> 6) & 63, b = n >> 12;
    const int c = lane * 4;
    const float* bp = in + (size_t)(b * HW) * CCH + c;
    float4 acc = *reinterpret_cast<const float4*>(bias + c);
    #pragma unroll
    for (int k = 0; k < 25; k++){
        const int dy = k / 5 - 2, dx = k % 5 - 2;
        const int yy = y + dy, xx = x + dx;
        const float m = (((unsigned)yy < 64u) & ((unsigned)xx < 64u)) ? 1.f : 0.f;
        const int yc = min(max(yy, 0), 63), xc = min(max(xx, 0), 63);
        const float4 iv = *reinterpret_cast<const float4*>(bp + (size_t)(yc * 64 + xc) * CCH);
        const float4 wv = *reinterpret_cast<const float4*>(wT + k * CCH + c);
        acc.x = fmaf(iv.x, wv.x * m, acc.x);
        acc.y = fmaf(iv.y, wv.y * m, acc.y);
        acc.z = fmaf(iv.z, wv.z * m, acc.z);
        acc.w = fmaf(iv.w, wv.w * m, acc.w);
    }
    *reinterpret_cast<float4*>(out + (size_t)n * CCH + c) = acc;
}

// ---------------- depthwise 3x3 + LayerNorm(channel) + GELU — branchless, wave-reduce ------
__global__ __launch_bounds__(256) void k_dw3_ln_gelu(const float* __restrict__ in,
                                                     const float* __restrict__ wT3,
                                                     const float* __restrict__ b3,
                                                     const float* __restrict__ g,
                                                     const float* __restrict__ bta,
                                                     float* __restrict__ out){
    const int lane = threadIdx.x & 63;
    const int pq   = threadIdx.x >> 6;
    const int n = blockIdx.x * 4 + pq;
    const int x = n & 63, y = (n >> 6) & 63, b = n >> 12;
    const int c = lane * 4;
    const float* bp = in + (size_t)(b * HW) * CCH + c;
    float4 acc = *reinterpret_cast<const float4*>(b3 + c);
    #pragma unroll
    for (int k = 0; k < 9; k++){
        const int dy = k / 3 - 1, dx = k % 3 - 1;
        const int yy = y + dy, xx = x + dx;
        const float m = (((unsigned)yy < 64u) & ((unsigned)xx < 64u)) ? 1.f : 0.f;
        const int yc = min(max(yy, 0), 63), xc = min(max(xx, 0), 63);
        const float4 iv = *reinterpret_cast<const float4*>(bp + (size_t)(yc * 64 + xc) * CCH);
        const float4 wv = *reinterpret_cast<const float4*>(wT3 + k * CCH + c);
        acc.x = fmaf(iv.x, wv.x * m, acc.x);
        acc.y = fmaf(iv.y, wv.y * m, acc.y);
        acc.z = fmaf(iv.z, wv.z * m, acc.z);
        acc.w = fmaf(iv.w, wv.w * m, acc.w);
    }
    float s  = acc.x + acc.y + acc.z + acc.w;
    float s2 = acc.x*acc.x + acc.y*acc.y + acc.z*acc.z + acc.w*acc.w;
    #pragma unroll
    for (int o = 32; o > 0; o >>= 1){
        s  += __shfl_xor(s, o);
        s2 += __shfl_xor(s2, o);
    }
    const float mu  = s  * (1.f / 256.f);
    const float var = s2 * (1.f / 256.f) - mu * mu;
    const float r   = rsqrtf(var + 1e-5f);
    const float4 gv = *reinterpret_cast<const float4*>(g + c);
    const float4 bv = *reinterpret_cast<const float4*>(bta + c);
    float4 o;
    o.x = gelu_f((acc.x - mu) * r * gv.x + bv.x);
    o.y = gelu_f((acc.y - mu) * r * gv.y + bv.y);
    o.z = gelu_f((acc.z - mu) * r * gv.z + bv.z);
    o.w = gelu_f((acc.w - mu) * r * gv.w + bv.w);
    *reinterpret_cast<float4*>(out + (size_t)n * CCH + c) = o;
}

// ---------------- DCNv3 core: fused softmax + bilinear sample + mask-weighted sum ----------
__global__ __launch_bounds__(256) void k_dcn(const float* __restrict__ xproj,
                                             const float* __restrict__ om,
                                             float* __restrict__ out){
    const int lane = threadIdx.x & 63;
    const int pq   = threadIdx.x >> 6;
    const int n = blockIdx.x * 4 + pq;
    const int gI = lane >> 3, cq = lane & 7;
    const int x = n & 63, y = (n >> 6) & 63, b = n >> 12;
    const float* off = om + (size_t)n * 216 + gI * 18;
    const float* lg  = om + (size_t)n * 216 + 144 + gI * 9;
    float l[9]; float mx = -1e30f;
    #pragma unroll
    for (int p = 0; p < 9; p++){ l[p] = lg[p]; mx = fmaxf(mx, l[p]); }
    float ssum = 0.f;
    #pragma unroll
    for (int p = 0; p < 9; p++){ l[p] = expf(l[p] - mx); ssum += l[p]; }
    const float inv = 1.f / ssum;
    const float* base = xproj + (size_t)b * HW * CCH + gI * 32 + cq * 4;
    float4 acc = {0.f, 0.f, 0.f, 0.f};
    #pragma unroll
    for (int p = 0; p < 9; p++){
        const float2 o2 = *reinterpret_cast<const float2*>(off + p * 2);
        const float ix = (float)(x + p / 3) + o2.x;
        const float iy = (float)(y + p % 3) + o2.y;
        const float x0f = floorf(ix), y0f = floorf(iy);
        const float wx1 = ix - x0f, wy1 = iy - y0f;
        const float wx0 = 1.f - wx1, wy0 = 1.f - wy1;
        const int ux = (int)x0f - 1, uy = (int)y0f - 1;
        const bool X0 = (unsigned)ux     < 64u, X1 = (unsigned)(ux+1) < 64u;
        const bool Y0 = (unsigned)uy     < 64u, Y1 = (unsigned)(uy+1) < 64u;
        const int ux0 = min(max(ux,     0), 63), ux1 = min(max(ux + 1, 0), 63);
        const int uy0 = min(max(uy,     0), 63), uy1 = min(max(uy + 1, 0), 63);
        const float mp = l[p] * inv;
        const float w00 = wx0 * wy0 * ((X0 & Y0) ? mp : 0.f);
        const float w01 = wx1 * wy0 * ((X1 & Y0) ? mp : 0.f);
        const float w10 = wx0 * wy1 * ((X0 & Y1) ? mp : 0.f);
        const float w11 = wx1 * wy1 * ((X1 & Y1) ? mp : 0.f);
        const float4 v00 = *reinterpret_cast<const float4*>(base + (size_t)(uy0 * 64 + ux0) * CCH);
        const float4 v01 = *reinterpret_cast<const float4*>(base + (size_t)(uy0 * 64 + ux1) * CCH);
        const float4 v10 = *reinterpret_cast<const float4*>(base + (size_t)(uy1 * 64 + ux0) * CCH);
        const float4 v11 = *reinterpret_cast<const float4*>(base + (size_t)(uy1 * 64 + ux1) * CCH);
        acc.x = fmaf(w00, v00.x, fmaf(w01, v01.x, fmaf(w10, v10.x, fmaf(w11, v11.x, acc.x))));
        acc.y = fmaf(w00, v00.y, fmaf(w01, v01.y, fmaf(w10, v10.y, fmaf(w11, v11.y, acc.y))));
        acc.z = fmaf(w00, v00.z, fmaf(w01, v01.z, fmaf(w10, v10.z, fmaf(w11, v11.z, acc.z))));
        acc.w = fmaf(w00, v00.w, fmaf(w01, v01.w, fmaf(w10, v10.w, fmaf(w11, v11.w, acc.w))));
    }
    *reinterpret_cast<float4*>(out + (size_t)n * CCH + gI * 32 + cq * 4) = acc;
}

extern "C" void kernel_launch(void* const* d_in, const int* in_sizes, int n_in,
                              void* d_out, int out_size, void* d_ws, size_t ws_size,
                              hipStream_t stream){
    const float* x         = (const float*)d_in[0];
    const float* proj1_w   = (const float*)d_in[1];
    const float* proj1_b   = (const float*)d_in[2];
    const float* conv0_w   = (const float*)d_in[3];
    const float* conv0_b   = (const float*)d_in[4];
    const float* inproj_w  = (const float*)d_in[5];
    const float* inproj_b  = (const float*)d_in[6];
    const float* dw_w      = (const float*)d_in[7];
    const float* dw_b      = (const float*)d_in[8];
    const float* ln_g      = (const float*)d_in[9];
    const float* ln_b      = (const float*)d_in[10];
    const float* off_w     = (const float*)d_in[11];
    const float* off_b     = (const float*)d_in[12];
    const float* mask_w    = (const float*)d_in[13];
    const float* mask_b    = (const float*)d_in[14];
    const float* outproj_w = (const float*)d_in[15];
    const float* outproj_b = (const float*)d_in[16];
    const float* conv_w    = (const float*)d_in[17];
    const float* conv_b    = (const float*)d_in[18];
    const float* proj2_w   = (const float*)d_in[19];
    const float* proj2_b   = (const float*)d_in[20];
    float* outp = (float*)d_out;

    const size_t NC = (size_t)NPIX * CCH;
    float* b0 = (float*)d_ws;      // x_t -> x1 -> dcnout
    float* b1 = b0 + NC;           // u (persists to the end)
    float* b2 = b1 + NC;           // h5 -> offset/mask(om) -> attn2
    float* b3 = outp;              // d_out as scratch: conv-wT -> xproj -> attn -> final
    unsigned short* wsp = (unsigned short*)(b2 + NC);   // 6 pairs of 256x256 bf16 hi/lo
    float* bcat = (float*)(wsp + 6 * 131072);           // 224 floats (off_b ++ mask_b ++ 0)
    float* wT   = b3;              // 25x256 conv5 weights (dead before xproj)
    float* wT3  = b3 + 25 * CCH;   // 9x256 conv3 weights

    const unsigned short* whi[6]; const unsigned short* wlo[6];
    for (int i = 0; i < 6; i++){ whi[i] = wsp + (size_t)i * 131072; wlo[i] = whi[i] + 65536; }

    const dim3 G(256, 2);

    // 0. weight preps (parallelized: 25 blocks / 96 blocks)
    k_prep<<<25,256,0,stream>>>(conv0_w, dw_w, wT, wT3);
    k_prep_w<<<dim3(16,6),256,0,stream>>>(proj1_w, inproj_w, outproj_w, conv_w, proj2_w,
                                          off_w, mask_w, off_b, mask_b, wsp, bcat);
    // 1. x (NCHW) -> NHWC
    k_transpose<<<dim3(64,4,4),256,0,stream>>>(x, b0);
    // 2. u = gelu(x @ proj1_w + b)
    k_gemm_bf<1,false><<<G,256,0,stream>>>(b0, nullptr, whi[0], wlo[0], proj1_b, nullptr, b1, 256, 256);
    // 3. h5 = dwconv5x5(u)
    k_dwconv5<<<4096,256,0,stream>>>(b1, wT, conv0_b, b2);
    // 4. x1 = gelu(LN(dwconv3x3(h5)))  (before xproj overwrites d_out head)
    k_dw3_ln_gelu<<<4096,256,0,stream>>>(b2, wT3, dw_b, ln_g, ln_b, b0);
    // 5. xproj = h5 @ inproj_w + b  -> d_out scratch
    k_gemm_bf<0,false><<<G,256,0,stream>>>(b2, nullptr, whi[1], wlo[1], inproj_b, nullptr, b3, 256, 256);
    // 6. offset||mask logits = x1 @ [off_w|mask_w] + b  (M=216, ld 216) into b2
    k_gemm_bf<0,false><<<G,256,0,stream>>>(b0, nullptr, whi[5], wlo[5], bcat, nullptr, b2, 216, 216);
    // 7. DCN core (softmax fused)
    k_dcn<<<4096,256,0,stream>>>(b3, b2, b0);
    // 8. attn = dcnout @ outproj_w + b
    k_gemm_bf<0,false><<<G,256,0,stream>>>(b0, nullptr, whi[2], wlo[2], outproj_b, nullptr, b3, 256, 256);
    // 9. attn2 = attn @ conv_w + b
    k_gemm_bf<0,false><<<G,256,0,stream>>>(b3, nullptr, whi[3], wlo[3], conv_b, nullptr, b2, 256, 256);
    // 10. out = (u * attn2) @ proj2_w + b + x   (NCHW write, fused residual)
    k_gemm_bf<2,true><<<G,256,0,stream>>>(b1, b2, whi[4], wlo[4], proj2_b, x, outp, 256, 256);
}